// Round 1
// baseline (2540.569 us; speedup 1.0000x reference)
//
#include <hip/hip_runtime.h>
#include <cfloat>

// PointNet / DGCNN: B=64, N=1024, F=5, W=128, K=2, D2=768
// Decomposition:
//   1. knn5      : top-2 on 5-dim x                          -> idx
//   2. conv1_l1  : h1[i,k] = relu(e @ p1_w1 + b1)  (F small, direct)
//   3. gemm128   : y1 = pairmax(relu(h1 @ p1_w2 + b2))   (fused max over k)
//   4. sqnorm/knn128 : top-2 on 128-dim y (fused Gram + top2)
//   5. gemm128x2 : U = y@W_top, V = y@W_bot
//   6. edge_max  : y' = max_k relu(U_i + V_jk - V_i + b)
//   7. pool / bn / 5x dense / out

__device__ __forceinline__ void top2_update(float& d1, int& j1, float& d2, int& j2,
                                            float dd, int j) {
  if (dd < d1 || (dd == d1 && j < j1)) { d2 = d1; j2 = j1; d1 = dd; j1 = j; }
  else if (dd < d2 || (dd == d2 && j < j2)) { d2 = dd; j2 = j; }
}

__device__ __forceinline__ void top2_reduce_wave(float& d1, int& j1, float& d2, int& j2) {
  #pragma unroll
  for (int m = 1; m < 64; m <<= 1) {
    float od1 = __shfl_xor(d1, m, 64); int oj1 = __shfl_xor(j1, m, 64);
    float od2 = __shfl_xor(d2, m, 64); int oj2 = __shfl_xor(j2, m, 64);
    bool aw = (d1 < od1) || (d1 == od1 && j1 < oj1);
    float h2d = aw ? d2 : od2;  int h2j = aw ? j2 : oj2;   // winner's 2nd
    float lmd = aw ? od1 : d1;  int lmj = aw ? oj1 : j1;   // loser's 1st
    float nd1 = aw ? d1 : od1;  int nj1 = aw ? j1 : oj1;
    bool bw = (h2d < lmd) || (h2d == lmd && h2j < lmj);
    d1 = nd1; j1 = nj1;
    d2 = bw ? h2d : lmd; j2 = bw ? h2j : lmj;
  }
}

// ---------------- KNN on 5-dim x: one wave per row ----------------
__global__ __launch_bounds__(256) void pn_knn5(const float* __restrict__ x,
                                               int* __restrict__ idx) {
  int wid = __builtin_amdgcn_readfirstlane((int)blockIdx.x * 4 + ((int)threadIdx.x >> 6));
  int lane = threadIdx.x & 63;
  const float* xb = x + (size_t)(wid >> 10) * (1024 * 5);
  const float* xi = x + (size_t)wid * 5;
  float x0 = xi[0], x1 = xi[1], x2 = xi[2], x3 = xi[3], x4 = xi[4];
  float d1 = FLT_MAX, d2 = FLT_MAX; int j1 = 0x7fffffff, j2 = 0x7fffffff;
  for (int tS = 0; tS < 16; ++tS) {
    int j = tS * 64 + lane;
    const float* xj = xb + (size_t)j * 5;
    float f0 = xj[0] - x0, f1 = xj[1] - x1, f2 = xj[2] - x2, f3 = xj[3] - x3, f4 = xj[4] - x4;
    float dd = f0*f0 + f1*f1 + f2*f2 + f3*f3 + f4*f4;
    top2_update(d1, j1, d2, j2, dd, j);
  }
  top2_reduce_wave(d1, j1, d2, j2);
  if (lane == 0) { idx[wid*2+0] = j1; idx[wid*2+1] = j2; }
}

// ---------------- conv1 layer1: h1[(i,k)][c] ----------------
__global__ __launch_bounds__(256) void pn_conv1_l1(const float* __restrict__ x,
                                                   const int* __restrict__ idx,
                                                   const float* __restrict__ w1,
                                                   const float* __restrict__ b1,
                                                   float* __restrict__ h1) {
  __shared__ float Ws[1280];
  __shared__ float Bs[128];
  for (int s = threadIdx.x; s < 1280; s += 256) Ws[s] = w1[s];
  if (threadIdx.x < 128) Bs[threadIdx.x] = b1[threadIdx.x];
  __syncthreads();
  int c = threadIdx.x & 127, rr = threadIdx.x >> 7;
  #pragma unroll
  for (int s = 0; s < 4; ++s) {
    int r = blockIdx.x * 8 + s * 2 + rr;     // row in [0,131072)
    int i = r >> 1, k = r & 1;
    int j = idx[i*2 + k];
    int jrow = ((i >> 10) << 10) + j;
    const float* xi = x + (size_t)i * 5;
    const float* xj = x + (size_t)jrow * 5;
    float acc = Bs[c];
    #pragma unroll
    for (int f = 0; f < 5; ++f) {
      float a = xi[f];
      float d = xj[f] - a;
      acc = fmaf(a, Ws[f*128 + c], acc);
      acc = fmaf(d, Ws[(5+f)*128 + c], acc);
    }
    h1[(size_t)r * 128 + c] = fmaxf(acc, 0.0f);
  }
}

// ---------------- GEMM: A[R,128] @ W[128,128] (+bias)(+relu)(+pairmax) ----------------
template<bool RELU, bool PAIRMAX>
__global__ __launch_bounds__(256) void pn_gemm128(const float* __restrict__ A,
                                                  const float* __restrict__ W,
                                                  const float* __restrict__ bias,
                                                  float* __restrict__ out) {
  __shared__ float As[32][132];   // [w][r], +4 pad
  __shared__ float Wsb[32][132];  // [w][c], +4 pad
  int t = threadIdx.x;
  int rg = t >> 4;   // 8-row group
  int cg = t & 15;   // cols cg*4..+3 and 64+cg*4..+3
  float acc[8][8];
  #pragma unroll
  for (int a = 0; a < 8; ++a)
    #pragma unroll
    for (int b = 0; b < 8; ++b) acc[a][b] = 0.f;
  size_t r0 = (size_t)blockIdx.x * 128;
  int ra = t >> 1, hf = t & 1;
  int wb = t >> 3, cp = t & 7;
  for (int w0 = 0; w0 < 128; w0 += 32) {
    const float* asrc = A + (r0 + ra) * 128 + w0 + hf * 16;
    #pragma unroll
    for (int q = 0; q < 4; ++q) {
      float4 v = ((const float4*)asrc)[q];
      int wi = hf * 16 + q * 4;
      As[wi+0][ra] = v.x; As[wi+1][ra] = v.y; As[wi+2][ra] = v.z; As[wi+3][ra] = v.w;
    }
    const float* wsrc = W + (size_t)(w0 + wb) * 128 + cp * 16;
    #pragma unroll
    for (int q = 0; q < 4; ++q)
      *(float4*)&Wsb[wb][cp*16 + q*4] = ((const float4*)wsrc)[q];
    __syncthreads();
    #pragma unroll
    for (int w = 0; w < 32; ++w) {
      float av[8], wv[8];
      *(float4*)&av[0] = *(const float4*)&As[w][rg*8];
      *(float4*)&av[4] = *(const float4*)&As[w][rg*8+4];
      *(float4*)&wv[0] = *(const float4*)&Wsb[w][cg*4];
      *(float4*)&wv[4] = *(const float4*)&Wsb[w][64 + cg*4];
      #pragma unroll
      for (int ri = 0; ri < 8; ++ri)
        #pragma unroll
        for (int ci = 0; ci < 8; ++ci)
          acc[ri][ci] = fmaf(av[ri], wv[ci], acc[ri][ci]);
    }
    __syncthreads();
  }
  float blo[4], bhi[4];
  #pragma unroll
  for (int ci = 0; ci < 4; ++ci) {
    blo[ci] = bias ? bias[cg*4 + ci] : 0.f;
    bhi[ci] = bias ? bias[64 + cg*4 + ci] : 0.f;
  }
  if (PAIRMAX) {
    #pragma unroll
    for (int ri = 0; ri < 8; ri += 2) {
      size_t orow = (r0 + rg*8 + ri) >> 1;
      float lo[4], hi[4];
      #pragma unroll
      for (int ci = 0; ci < 4; ++ci) {
        float v0 = acc[ri][ci]   + blo[ci];
        float v1 = acc[ri+1][ci] + blo[ci];
        lo[ci] = fmaxf(fmaxf(v0, v1), 0.f);
        float w0v = acc[ri][ci+4]   + bhi[ci];
        float w1v = acc[ri+1][ci+4] + bhi[ci];
        hi[ci] = fmaxf(fmaxf(w0v, w1v), 0.f);
      }
      *(float4*)&out[orow*128 + cg*4]      = *(float4*)lo;
      *(float4*)&out[orow*128 + 64 + cg*4] = *(float4*)hi;
    }
  } else {
    #pragma unroll
    for (int ri = 0; ri < 8; ++ri) {
      size_t row = r0 + rg*8 + ri;
      float lo[4], hi[4];
      #pragma unroll
      for (int ci = 0; ci < 4; ++ci) {
        float v0 = acc[ri][ci]   + blo[ci];
        float v1 = acc[ri][ci+4] + bhi[ci];
        lo[ci] = RELU ? fmaxf(v0, 0.f) : v0;
        hi[ci] = RELU ? fmaxf(v1, 0.f) : v1;
      }
      *(float4*)&out[row*128 + cg*4]      = *(float4*)lo;
      *(float4*)&out[row*128 + 64 + cg*4] = *(float4*)hi;
    }
  }
}

// ---------------- row squared norms ----------------
__global__ __launch_bounds__(256) void pn_sqnorm(const float* __restrict__ y,
                                                 float* __restrict__ sq) {
  int r = blockIdx.x * 256 + threadIdx.x;
  const float4* p = (const float4*)(y + (size_t)r * 128);
  float s = 0.f;
  #pragma unroll
  for (int q = 0; q < 32; ++q) {
    float4 v = p[q];
    s += v.x*v.x + v.y*v.y + v.z*v.z + v.w*v.w;
  }
  sq[r] = s;
}

// ---------------- KNN on 128-dim y: fused Gram + top-2 ----------------
// block = 256 thr (4 waves x 8 i-rows = 32 i), j-tiles of 64 staged in LDS.
__global__ __launch_bounds__(256) void pn_knn128(const float* __restrict__ Y,
                                                 const float* __restrict__ sqn,
                                                 int* __restrict__ idx) {
  __shared__ float yj[64][132];  // +4 pad -> conflict-free b128
  __shared__ float sqs[64];
  int t = threadIdx.x, lane = t & 63;
  int b = blockIdx.x >> 5;
  int itile = blockIdx.x & 31;
  int wv = __builtin_amdgcn_readfirstlane(t >> 6);
  int i0 = itile * 32 + wv * 8;
  const float* Yb = Y + (size_t)b * (1024 * 128);
  const float* sqb = sqn + b * 1024;
  float sqi[8];
  #pragma unroll
  for (int ii = 0; ii < 8; ++ii) sqi[ii] = sqb[i0 + ii];
  float d1[8], d2[8]; int j1[8], j2[8];
  #pragma unroll
  for (int ii = 0; ii < 8; ++ii) {
    d1[ii] = FLT_MAX; d2[ii] = FLT_MAX; j1[ii] = 0x7fffffff; j2[ii] = 0x7fffffff;
  }
  for (int jt = 0; jt < 16; ++jt) {
    __syncthreads();
    #pragma unroll
    for (int s = 0; s < 8; ++s) {
      int g = t + 256 * s;
      int r = g >> 5, c4 = (g & 31) << 2;
      *(float4*)&yj[r][c4] = *(const float4*)&Yb[(size_t)(jt*64 + r) * 128 + c4];
    }
    if (t < 64) sqs[t] = sqb[jt*64 + t];
    __syncthreads();
    int j = jt * 64 + lane;
    float acc[8] = {0.f,0.f,0.f,0.f,0.f,0.f,0.f,0.f};
    #pragma unroll 4
    for (int d4 = 0; d4 < 32; ++d4) {
      float4 vj = *(const float4*)&yj[lane][d4 << 2];
      #pragma unroll
      for (int ii = 0; ii < 8; ++ii) {
        const float* yi = Yb + (size_t)(i0 + ii) * 128 + (d4 << 2);  // uniform -> s_load
        acc[ii] = fmaf(yi[0], vj.x, acc[ii]);
        acc[ii] = fmaf(yi[1], vj.y, acc[ii]);
        acc[ii] = fmaf(yi[2], vj.z, acc[ii]);
        acc[ii] = fmaf(yi[3], vj.w, acc[ii]);
      }
    }
    float sj = sqs[lane];
    #pragma unroll
    for (int ii = 0; ii < 8; ++ii) {
      float dd = sqi[ii] + sj - 2.0f * acc[ii];
      top2_update(d1[ii], j1[ii], d2[ii], j2[ii], dd, j);
    }
  }
  #pragma unroll
  for (int ii = 0; ii < 8; ++ii) {
    top2_reduce_wave(d1[ii], j1[ii], d2[ii], j2[ii]);
    if (lane == 0) {
      int ri = b*1024 + i0 + ii;
      idx[ri*2+0] = j1[ii];
      idx[ri*2+1] = j2[ii];
    }
  }
}

// ---------------- edge epilogue: y = max_k relu(U_i + V_jk - V_i + b) ----------------
__global__ __launch_bounds__(256) void pn_edge_max(const float* __restrict__ U,
                                                   const float* __restrict__ V,
                                                   const int* __restrict__ idx,
                                                   const float* __restrict__ bias,
                                                   float* __restrict__ y) {
  int gid = blockIdx.x * 256 + threadIdx.x;
  int i = gid >> 5, c4 = (gid & 31) << 2;
  int base = (i >> 10) << 10;
  int j0 = idx[i*2+0], j1 = idx[i*2+1];
  float4 u  = *(const float4*)&U[(size_t)i*128 + c4];
  float4 vi = *(const float4*)&V[(size_t)i*128 + c4];
  float4 v0 = *(const float4*)&V[(size_t)(base + j0)*128 + c4];
  float4 v1 = *(const float4*)&V[(size_t)(base + j1)*128 + c4];
  float4 bb = *(const float4*)&bias[c4];
  float4 o;
  o.x = fmaxf(fmaxf(u.x + v0.x - vi.x + bb.x, u.x + v1.x - vi.x + bb.x), 0.f);
  o.y = fmaxf(fmaxf(u.y + v0.y - vi.y + bb.y, u.y + v1.y - vi.y + bb.y), 0.f);
  o.z = fmaxf(fmaxf(u.z + v0.z - vi.z + bb.z, u.z + v1.z - vi.z + bb.z), 0.f);
  o.w = fmaxf(fmaxf(u.w + v0.w - vi.w + bb.w, u.w + v1.w - vi.w + bb.w), 0.f);
  *(float4*)&y[(size_t)i*128 + c4] = o;
}

// ---------------- pooling: g[b] = [mean_n ycat | max_n ycat] ----------------
__global__ __launch_bounds__(384) void pn_pool(const float* __restrict__ y1,
                                               const float* __restrict__ y2,
                                               const float* __restrict__ y3,
                                               float* __restrict__ g) {
  int b = blockIdx.x, c = threadIdx.x;
  const float* src = (c < 128) ? (y1 + (size_t)b * 1024 * 128 + c)
                   : (c < 256) ? (y2 + (size_t)b * 1024 * 128 + (c - 128))
                               : (y3 + (size_t)b * 1024 * 128 + (c - 256));
  float s = 0.f, mx = -FLT_MAX;
  for (int n = 0; n < 1024; ++n) {
    float v = src[(size_t)n * 128];
    s += v; mx = fmaxf(mx, v);
  }
  g[b*768 + c] = s * (1.0f / 1024.0f);
  g[b*768 + 384 + c] = mx;
}

// ---------------- batchnorm over B=64 (training stats, biased var) ----------------
__global__ __launch_bounds__(256) void pn_bn(const float* __restrict__ g,
                                             const float* __restrict__ gamma,
                                             const float* __restrict__ beta,
                                             float* __restrict__ out) {
  int c = blockIdx.x * 256 + threadIdx.x;
  float mu = 0.f;
  for (int b = 0; b < 64; ++b) mu += g[b*768 + c];
  mu *= (1.0f / 64.0f);
  float var = 0.f;
  for (int b = 0; b < 64; ++b) { float d = g[b*768 + c] - mu; var += d * d; }
  var *= (1.0f / 64.0f);
  float sc = (1.0f / sqrtf(var + 1e-5f)) * gamma[c];
  float sh = beta[c];
  for (int b = 0; b < 64; ++b) out[b*768 + c] = (g[b*768 + c] - mu) * sc + sh;
}

// ---------------- dense 768->768 (+leaky) ----------------
__global__ __launch_bounds__(256) void pn_dense(const float* __restrict__ h,
                                                const float* __restrict__ W,
                                                const float* __restrict__ bias,
                                                float* __restrict__ out) {
  int b = blockIdx.x / 3;
  int c = (blockIdx.x % 3) * 256 + threadIdx.x;
  const float* hb = h + (size_t)b * 768;  // uniform row -> s_load
  float acc = bias[c];
  for (int w = 0; w < 768; ++w) acc = fmaf(hb[w], W[(size_t)w*768 + c], acc);
  acc = acc > 0.f ? acc : 0.01f * acc;
  out[b*768 + c] = acc;
}

// ---------------- final 768->1 ----------------
__global__ __launch_bounds__(256) void pn_out(const float* __restrict__ h,
                                              const float* __restrict__ ow,
                                              const float* __restrict__ ob,
                                              float* __restrict__ out) {
  int wid = blockIdx.x * 4 + (threadIdx.x >> 6);
  int lane = threadIdx.x & 63;
  const float* hb = h + (size_t)wid * 768;
  float s = 0.f;
  #pragma unroll
  for (int q = 0; q < 12; ++q) {
    int w = q * 64 + lane;
    s = fmaf(hb[w], ow[w], s);
  }
  #pragma unroll
  for (int m = 1; m < 64; m <<= 1) s += __shfl_xor(s, m, 64);
  if (lane == 0) out[wid] = s + ob[0];
}

extern "C" void kernel_launch(void* const* d_in, const int* in_sizes, int n_in,
                              void* d_out, int out_size, void* d_ws, size_t ws_size,
                              hipStream_t stream) {
  (void)in_sizes; (void)n_in; (void)out_size; (void)ws_size;
  const float* x     = (const float*)d_in[0];
  const float* p1w1  = (const float*)d_in[1];
  const float* p1b1  = (const float*)d_in[2];
  const float* p1w2  = (const float*)d_in[3];
  const float* p1b2  = (const float*)d_in[4];
  const float* cw    = (const float*)d_in[5];   // [2][256][128]
  const float* cb    = (const float*)d_in[6];   // [2][128]
  const float* bng   = (const float*)d_in[7];
  const float* bnb   = (const float*)d_in[8];
  const float* linw  = (const float*)d_in[9];   // [5][768][768]
  const float* linb  = (const float*)d_in[10];  // [5][768]
  const float* outw  = (const float*)d_in[11];  // [768]
  const float* outb  = (const float*)d_in[12];  // [1]
  float* outp = (float*)d_out;

  // workspace layout (floats)
  float* ws = (float*)d_ws;
  const size_t YSZ = (size_t)65536 * 128;  // 8388608
  float* y1 = ws;
  float* y2 = y1 + YSZ;
  float* y3 = y2 + YSZ;
  float* U  = y3 + YSZ;
  float* V  = U + YSZ;
  float* h1 = U;                 // h1 [131072,128] overlaps U+V (used before them)
  float* sq = V + YSZ;
  int*   idxb = (int*)(sq + 65536);
  float* g  = (float*)(idxb + 131072);
  float* ha = g + 49152;
  float* hb = ha + 49152;

  // --- conv1 ---
  pn_knn5<<<16384, 256, 0, stream>>>(x, idxb);
  pn_conv1_l1<<<16384, 256, 0, stream>>>(x, idxb, p1w1, p1b1, h1);
  pn_gemm128<true, true><<<1024, 256, 0, stream>>>(h1, p1w2, p1b2, y1);
  // --- conv2 ---
  pn_sqnorm<<<256, 256, 0, stream>>>(y1, sq);
  pn_knn128<<<2048, 256, 0, stream>>>(y1, sq, idxb);
  pn_gemm128<false, false><<<512, 256, 0, stream>>>(y1, cw,          nullptr, U);
  pn_gemm128<false, false><<<512, 256, 0, stream>>>(y1, cw + 16384,  nullptr, V);
  pn_edge_max<<<8192, 256, 0, stream>>>(U, V, idxb, cb, y2);
  // --- conv3 ---
  pn_sqnorm<<<256, 256, 0, stream>>>(y2, sq);
  pn_knn128<<<2048, 256, 0, stream>>>(y2, sq, idxb);
  pn_gemm128<false, false><<<512, 256, 0, stream>>>(y2, cw + 32768,  nullptr, U);
  pn_gemm128<false, false><<<512, 256, 0, stream>>>(y2, cw + 49152,  nullptr, V);
  pn_edge_max<<<8192, 256, 0, stream>>>(U, V, idxb, cb + 128, y3);
  // --- head ---
  pn_pool<<<64, 384, 0, stream>>>(y1, y2, y3, g);
  pn_bn<<<3, 256, 0, stream>>>(g, bng, bnb, ha);
  pn_dense<<<192, 256, 0, stream>>>(ha, linw + 0*589824, linb + 0*768, hb);
  pn_dense<<<192, 256, 0, stream>>>(hb, linw + 1*589824, linb + 1*768, ha);
  pn_dense<<<192, 256, 0, stream>>>(ha, linw + 2*589824, linb + 2*768, hb);
  pn_dense<<<192, 256, 0, stream>>>(hb, linw + 3*589824, linb + 3*768, ha);
  pn_dense<<<192, 256, 0, stream>>>(ha, linw + 4*589824, linb + 4*768, hb);
  pn_out<<<16, 256, 0, stream>>>(hb, outw, outb, outp);
}

// Round 2
// 1855.884 us; speedup vs baseline: 1.3689x; 1.3689x over previous
//
#include <hip/hip_runtime.h>
#include <cfloat>

// PointNet / DGCNN: B=64, N=1024, F=5, W=128, K=2, D2=768
// R2: pn_knn128 rewritten as register-tiled GEMM (128x128 tile, 8x8/thread,
//     transposed LDS staging) with fused top-2 epilogue. FMA k-order ascending
//     -> bit-identical to R1's distances (which matched np exactly).

__device__ __forceinline__ void top2_update(float& d1, int& j1, float& d2, int& j2,
                                            float dd, int j) {
  if (dd < d1 || (dd == d1 && j < j1)) { d2 = d1; j2 = j1; d1 = dd; j1 = j; }
  else if (dd < d2 || (dd == d2 && j < j2)) { d2 = dd; j2 = j; }
}

__device__ __forceinline__ void top2_merge_xor(float& d1, int& j1, float& d2, int& j2, int m) {
  float od1 = __shfl_xor(d1, m, 64); int oj1 = __shfl_xor(j1, m, 64);
  float od2 = __shfl_xor(d2, m, 64); int oj2 = __shfl_xor(j2, m, 64);
  bool aw = (d1 < od1) || (d1 == od1 && j1 < oj1);
  float h2d = aw ? d2 : od2;  int h2j = aw ? j2 : oj2;   // winner's 2nd
  float lmd = aw ? od1 : d1;  int lmj = aw ? oj1 : j1;   // loser's 1st
  float nd1 = aw ? d1 : od1;  int nj1 = aw ? j1 : oj1;
  bool bw = (h2d < lmd) || (h2d == lmd && h2j < lmj);
  d1 = nd1; j1 = nj1;
  d2 = bw ? h2d : lmd; j2 = bw ? h2j : lmj;
}

__device__ __forceinline__ void top2_reduce_wave(float& d1, int& j1, float& d2, int& j2) {
  #pragma unroll
  for (int m = 1; m < 64; m <<= 1) top2_merge_xor(d1, j1, d2, j2, m);
}

// ---------------- KNN on 5-dim x: one wave per row ----------------
__global__ __launch_bounds__(256) void pn_knn5(const float* __restrict__ x,
                                               int* __restrict__ idx) {
  int wid = __builtin_amdgcn_readfirstlane((int)blockIdx.x * 4 + ((int)threadIdx.x >> 6));
  int lane = threadIdx.x & 63;
  const float* xb = x + (size_t)(wid >> 10) * (1024 * 5);
  const float* xi = x + (size_t)wid * 5;
  float x0 = xi[0], x1 = xi[1], x2 = xi[2], x3 = xi[3], x4 = xi[4];
  float d1 = FLT_MAX, d2 = FLT_MAX; int j1 = 0x7fffffff, j2 = 0x7fffffff;
  for (int tS = 0; tS < 16; ++tS) {
    int j = tS * 64 + lane;
    const float* xj = xb + (size_t)j * 5;
    float f0 = xj[0] - x0, f1 = xj[1] - x1, f2 = xj[2] - x2, f3 = xj[3] - x3, f4 = xj[4] - x4;
    float dd = f0*f0 + f1*f1 + f2*f2 + f3*f3 + f4*f4;
    top2_update(d1, j1, d2, j2, dd, j);
  }
  top2_reduce_wave(d1, j1, d2, j2);
  if (lane == 0) { idx[wid*2+0] = j1; idx[wid*2+1] = j2; }
}

// ---------------- conv1 layer1: h1[(i,k)][c] ----------------
__global__ __launch_bounds__(256) void pn_conv1_l1(const float* __restrict__ x,
                                                   const int* __restrict__ idx,
                                                   const float* __restrict__ w1,
                                                   const float* __restrict__ b1,
                                                   float* __restrict__ h1) {
  __shared__ float Ws[1280];
  __shared__ float Bs[128];
  for (int s = threadIdx.x; s < 1280; s += 256) Ws[s] = w1[s];
  if (threadIdx.x < 128) Bs[threadIdx.x] = b1[threadIdx.x];
  __syncthreads();
  int c = threadIdx.x & 127, rr = threadIdx.x >> 7;
  #pragma unroll
  for (int s = 0; s < 4; ++s) {
    int r = blockIdx.x * 8 + s * 2 + rr;     // row in [0,131072)
    int i = r >> 1, k = r & 1;
    int j = idx[i*2 + k];
    int jrow = ((i >> 10) << 10) + j;
    const float* xi = x + (size_t)i * 5;
    const float* xj = x + (size_t)jrow * 5;
    float acc = Bs[c];
    #pragma unroll
    for (int f = 0; f < 5; ++f) {
      float a = xi[f];
      float d = xj[f] - a;
      acc = fmaf(a, Ws[f*128 + c], acc);
      acc = fmaf(d, Ws[(5+f)*128 + c], acc);
    }
    h1[(size_t)r * 128 + c] = fmaxf(acc, 0.0f);
  }
}

// ---------------- GEMM: A[R,128] @ W[128,128] (+bias)(+relu)(+pairmax) ----------------
template<bool RELU, bool PAIRMAX>
__global__ __launch_bounds__(256) void pn_gemm128(const float* __restrict__ A,
                                                  const float* __restrict__ W,
                                                  const float* __restrict__ bias,
                                                  float* __restrict__ out) {
  __shared__ float As[32][132];   // [w][r], +4 pad
  __shared__ float Wsb[32][132];  // [w][c], +4 pad
  int t = threadIdx.x;
  int rg = t >> 4;   // 8-row group
  int cg = t & 15;   // cols cg*4..+3 and 64+cg*4..+3
  float acc[8][8];
  #pragma unroll
  for (int a = 0; a < 8; ++a)
    #pragma unroll
    for (int b = 0; b < 8; ++b) acc[a][b] = 0.f;
  size_t r0 = (size_t)blockIdx.x * 128;
  int ra = t >> 1, hf = t & 1;
  int wb = t >> 3, cp = t & 7;
  for (int w0 = 0; w0 < 128; w0 += 32) {
    const float* asrc = A + (r0 + ra) * 128 + w0 + hf * 16;
    #pragma unroll
    for (int q = 0; q < 4; ++q) {
      float4 v = ((const float4*)asrc)[q];
      int wi = hf * 16 + q * 4;
      As[wi+0][ra] = v.x; As[wi+1][ra] = v.y; As[wi+2][ra] = v.z; As[wi+3][ra] = v.w;
    }
    const float* wsrc = W + (size_t)(w0 + wb) * 128 + cp * 16;
    #pragma unroll
    for (int q = 0; q < 4; ++q)
      *(float4*)&Wsb[wb][cp*16 + q*4] = ((const float4*)wsrc)[q];
    __syncthreads();
    #pragma unroll
    for (int w = 0; w < 32; ++w) {
      float av[8], wv[8];
      *(float4*)&av[0] = *(const float4*)&As[w][rg*8];
      *(float4*)&av[4] = *(const float4*)&As[w][rg*8+4];
      *(float4*)&wv[0] = *(const float4*)&Wsb[w][cg*4];
      *(float4*)&wv[4] = *(const float4*)&Wsb[w][64 + cg*4];
      #pragma unroll
      for (int ri = 0; ri < 8; ++ri)
        #pragma unroll
        for (int ci = 0; ci < 8; ++ci)
          acc[ri][ci] = fmaf(av[ri], wv[ci], acc[ri][ci]);
    }
    __syncthreads();
  }
  float blo[4], bhi[4];
  #pragma unroll
  for (int ci = 0; ci < 4; ++ci) {
    blo[ci] = bias ? bias[cg*4 + ci] : 0.f;
    bhi[ci] = bias ? bias[64 + cg*4 + ci] : 0.f;
  }
  if (PAIRMAX) {
    #pragma unroll
    for (int ri = 0; ri < 8; ri += 2) {
      size_t orow = (r0 + rg*8 + ri) >> 1;
      float lo[4], hi[4];
      #pragma unroll
      for (int ci = 0; ci < 4; ++ci) {
        float v0 = acc[ri][ci]   + blo[ci];
        float v1 = acc[ri+1][ci] + blo[ci];
        lo[ci] = fmaxf(fmaxf(v0, v1), 0.f);
        float w0v = acc[ri][ci+4]   + bhi[ci];
        float w1v = acc[ri+1][ci+4] + bhi[ci];
        hi[ci] = fmaxf(fmaxf(w0v, w1v), 0.f);
      }
      *(float4*)&out[orow*128 + cg*4]      = *(float4*)lo;
      *(float4*)&out[orow*128 + 64 + cg*4] = *(float4*)hi;
    }
  } else {
    #pragma unroll
    for (int ri = 0; ri < 8; ++ri) {
      size_t row = r0 + rg*8 + ri;
      float lo[4], hi[4];
      #pragma unroll
      for (int ci = 0; ci < 4; ++ci) {
        float v0 = acc[ri][ci]   + blo[ci];
        float v1 = acc[ri][ci+4] + bhi[ci];
        lo[ci] = RELU ? fmaxf(v0, 0.f) : v0;
        hi[ci] = RELU ? fmaxf(v1, 0.f) : v1;
      }
      *(float4*)&out[row*128 + cg*4]      = *(float4*)lo;
      *(float4*)&out[row*128 + 64 + cg*4] = *(float4*)hi;
    }
  }
}

// ---------------- row squared norms ----------------
__global__ __launch_bounds__(256) void pn_sqnorm(const float* __restrict__ y,
                                                 float* __restrict__ sq) {
  int r = blockIdx.x * 256 + threadIdx.x;
  const float4* p = (const float4*)(y + (size_t)r * 128);
  float s = 0.f;
  #pragma unroll
  for (int q = 0; q < 32; ++q) {
    float4 v = p[q];
    s += v.x*v.x + v.y*v.y + v.z*v.z + v.w*v.w;
  }
  sq[r] = s;
}

// ---------------- KNN on 128-dim y: register-tiled Gram GEMM + fused top-2 ----
// grid = B * 8 (i-tiles of 128). 256 thr: rg=t>>4 (8 i-rows), cg=t&15
// (j cols cg*4..+3 and 64+cg*4..+3). k staged transposed in LDS, chunks of 32.
__global__ __launch_bounds__(256) void pn_knn128(const float* __restrict__ Y,
                                                 const float* __restrict__ sqn,
                                                 int* __restrict__ idx) {
  __shared__ float As[32][132];   // [k][i], +4 pad
  __shared__ float Bs[32][132];   // [k][j], +4 pad
  __shared__ float sqjs[128];
  int t = threadIdx.x;
  int rg = t >> 4, cg = t & 15;
  int b = blockIdx.x >> 3;
  int itile = blockIdx.x & 7;
  int i0 = itile * 128;
  const float* Yb = Y + (size_t)b * (1024 * 128);
  const float* sqb = sqn + b * 1024;
  float sqi[8];
  #pragma unroll
  for (int ri = 0; ri < 8; ++ri) sqi[ri] = sqb[i0 + rg*8 + ri];
  float d1[8], d2[8]; int j1[8], j2[8];
  #pragma unroll
  for (int ri = 0; ri < 8; ++ri) {
    d1[ri] = FLT_MAX; d2[ri] = FLT_MAX; j1[ri] = 0x7fffffff; j2[ri] = 0x7fffffff;
  }
  int si = t >> 3, skq = t & 7;   // staging: 8 lanes cover one row's 32 k-floats

  for (int jt = 0; jt < 8; ++jt) {
    int j0 = jt * 128;
    __syncthreads();              // protect sqjs (+ LDS) from previous tile readers
    if (t < 128) sqjs[t] = sqb[j0 + t];
    float acc[8][8];
    #pragma unroll
    for (int a = 0; a < 8; ++a)
      #pragma unroll
      for (int c = 0; c < 8; ++c) acc[a][c] = 0.f;

    for (int k0 = 0; k0 < 128; k0 += 32) {
      // stage A (i-rows) and B (j-rows), transposed [k][row]
      #pragma unroll
      for (int q = 0; q < 4; ++q) {
        int g = t + 256 * q;                 // 0..1023
        int row = g >> 3, kq = g & 7;
        float4 va = *(const float4*)&Yb[(size_t)(i0 + row) * 128 + k0 + kq * 4];
        float4 vb = *(const float4*)&Yb[(size_t)(j0 + row) * 128 + k0 + kq * 4];
        int kk = kq * 4;
        As[kk+0][row] = va.x; As[kk+1][row] = va.y; As[kk+2][row] = va.z; As[kk+3][row] = va.w;
        Bs[kk+0][row] = vb.x; Bs[kk+1][row] = vb.y; Bs[kk+2][row] = vb.z; Bs[kk+3][row] = vb.w;
      }
      __syncthreads();
      #pragma unroll
      for (int k = 0; k < 32; ++k) {
        float av[8], bv[8];
        *(float4*)&av[0] = *(const float4*)&As[k][rg*8];
        *(float4*)&av[4] = *(const float4*)&As[k][rg*8+4];
        *(float4*)&bv[0] = *(const float4*)&Bs[k][cg*4];
        *(float4*)&bv[4] = *(const float4*)&Bs[k][64 + cg*4];
        #pragma unroll
        for (int ri = 0; ri < 8; ++ri)
          #pragma unroll
          for (int ci = 0; ci < 8; ++ci)
            acc[ri][ci] = fmaf(av[ri], bv[ci], acc[ri][ci]);
      }
      __syncthreads();
    }
    // fused top-2 epilogue for this j-tile (j ascending within thread)
    #pragma unroll
    for (int ri = 0; ri < 8; ++ri) {
      #pragma unroll
      for (int ci = 0; ci < 4; ++ci) {
        int j = j0 + cg*4 + ci;
        float dd = sqi[ri] + sqjs[cg*4 + ci] - 2.0f * acc[ri][ci];
        top2_update(d1[ri], j1[ri], d2[ri], j2[ri], dd, j);
      }
      #pragma unroll
      for (int ci = 0; ci < 4; ++ci) {
        int j = j0 + 64 + cg*4 + ci;
        float dd = sqi[ri] + sqjs[64 + cg*4 + ci] - 2.0f * acc[ri][ci+4];
        top2_update(d1[ri], j1[ri], d2[ri], j2[ri], dd, j);
      }
    }
  }
  // merge across the 16 cg-lanes (same rg = lanes rg*16..rg*16+15 of a wave)
  #pragma unroll
  for (int ri = 0; ri < 8; ++ri) {
    top2_merge_xor(d1[ri], j1[ri], d2[ri], j2[ri], 1);
    top2_merge_xor(d1[ri], j1[ri], d2[ri], j2[ri], 2);
    top2_merge_xor(d1[ri], j1[ri], d2[ri], j2[ri], 4);
    top2_merge_xor(d1[ri], j1[ri], d2[ri], j2[ri], 8);
    if (cg == 0) {
      int row = b * 1024 + i0 + rg*8 + ri;
      idx[row*2+0] = j1[ri];
      idx[row*2+1] = j2[ri];
    }
  }
}

// ---------------- edge epilogue: y = max_k relu(U_i + V_jk - V_i + b) ----------------
__global__ __launch_bounds__(256) void pn_edge_max(const float* __restrict__ U,
                                                   const float* __restrict__ V,
                                                   const int* __restrict__ idx,
                                                   const float* __restrict__ bias,
                                                   float* __restrict__ y) {
  int gid = blockIdx.x * 256 + threadIdx.x;
  int i = gid >> 5, c4 = (gid & 31) << 2;
  int base = (i >> 10) << 10;
  int j0 = idx[i*2+0], j1 = idx[i*2+1];
  float4 u  = *(const float4*)&U[(size_t)i*128 + c4];
  float4 vi = *(const float4*)&V[(size_t)i*128 + c4];
  float4 v0 = *(const float4*)&V[(size_t)(base + j0)*128 + c4];
  float4 v1 = *(const float4*)&V[(size_t)(base + j1)*128 + c4];
  float4 bb = *(const float4*)&bias[c4];
  float4 o;
  o.x = fmaxf(fmaxf(u.x + v0.x - vi.x + bb.x, u.x + v1.x - vi.x + bb.x), 0.f);
  o.y = fmaxf(fmaxf(u.y + v0.y - vi.y + bb.y, u.y + v1.y - vi.y + bb.y), 0.f);
  o.z = fmaxf(fmaxf(u.z + v0.z - vi.z + bb.z, u.z + v1.z - vi.z + bb.z), 0.f);
  o.w = fmaxf(fmaxf(u.w + v0.w - vi.w + bb.w, u.w + v1.w - vi.w + bb.w), 0.f);
  *(float4*)&y[(size_t)i*128 + c4] = o;
}

// ---------------- pooling: g[b] = [mean_n ycat | max_n ycat] ----------------
__global__ __launch_bounds__(384) void pn_pool(const float* __restrict__ y1,
                                               const float* __restrict__ y2,
                                               const float* __restrict__ y3,
                                               float* __restrict__ g) {
  int b = blockIdx.x, c = threadIdx.x;
  const float* src = (c < 128) ? (y1 + (size_t)b * 1024 * 128 + c)
                   : (c < 256) ? (y2 + (size_t)b * 1024 * 128 + (c - 128))
                               : (y3 + (size_t)b * 1024 * 128 + (c - 256));
  float s = 0.f, mx = -FLT_MAX;
  for (int n = 0; n < 1024; ++n) {
    float v = src[(size_t)n * 128];
    s += v; mx = fmaxf(mx, v);
  }
  g[b*768 + c] = s * (1.0f / 1024.0f);
  g[b*768 + 384 + c] = mx;
}

// ---------------- batchnorm over B=64 (training stats, biased var) ----------------
__global__ __launch_bounds__(256) void pn_bn(const float* __restrict__ g,
                                             const float* __restrict__ gamma,
                                             const float* __restrict__ beta,
                                             float* __restrict__ out) {
  int c = blockIdx.x * 256 + threadIdx.x;
  float mu = 0.f;
  for (int b = 0; b < 64; ++b) mu += g[b*768 + c];
  mu *= (1.0f / 64.0f);
  float var = 0.f;
  for (int b = 0; b < 64; ++b) { float d = g[b*768 + c] - mu; var += d * d; }
  var *= (1.0f / 64.0f);
  float sc = (1.0f / sqrtf(var + 1e-5f)) * gamma[c];
  float sh = beta[c];
  for (int b = 0; b < 64; ++b) out[b*768 + c] = (g[b*768 + c] - mu) * sc + sh;
}

// ---------------- dense 768->768 (+leaky) ----------------
__global__ __launch_bounds__(256) void pn_dense(const float* __restrict__ h,
                                                const float* __restrict__ W,
                                                const float* __restrict__ bias,
                                                float* __restrict__ out) {
  int b = blockIdx.x / 3;
  int c = (blockIdx.x % 3) * 256 + threadIdx.x;
  const float* hb = h + (size_t)b * 768;  // uniform row -> s_load
  float acc = bias[c];
  for (int w = 0; w < 768; ++w) acc = fmaf(hb[w], W[(size_t)w*768 + c], acc);
  acc = acc > 0.f ? acc : 0.01f * acc;
  out[b*768 + c] = acc;
}

// ---------------- final 768->1 ----------------
__global__ __launch_bounds__(256) void pn_out(const float* __restrict__ h,
                                              const float* __restrict__ ow,
                                              const float* __restrict__ ob,
                                              float* __restrict__ out) {
  int wid = blockIdx.x * 4 + (threadIdx.x >> 6);
  int lane = threadIdx.x & 63;
  const float* hb = h + (size_t)wid * 768;
  float s = 0.f;
  #pragma unroll
  for (int q = 0; q < 12; ++q) {
    int w = q * 64 + lane;
    s = fmaf(hb[w], ow[w], s);
  }
  #pragma unroll
  for (int m = 1; m < 64; m <<= 1) s += __shfl_xor(s, m, 64);
  if (lane == 0) out[wid] = s + ob[0];
}

extern "C" void kernel_launch(void* const* d_in, const int* in_sizes, int n_in,
                              void* d_out, int out_size, void* d_ws, size_t ws_size,
                              hipStream_t stream) {
  (void)in_sizes; (void)n_in; (void)out_size; (void)ws_size;
  const float* x     = (const float*)d_in[0];
  const float* p1w1  = (const float*)d_in[1];
  const float* p1b1  = (const float*)d_in[2];
  const float* p1w2  = (const float*)d_in[3];
  const float* p1b2  = (const float*)d_in[4];
  const float* cw    = (const float*)d_in[5];   // [2][256][128]
  const float* cb    = (const float*)d_in[6];   // [2][128]
  const float* bng   = (const float*)d_in[7];
  const float* bnb   = (const float*)d_in[8];
  const float* linw  = (const float*)d_in[9];   // [5][768][768]
  const float* linb  = (const float*)d_in[10];  // [5][768]
  const float* outw  = (const float*)d_in[11];  // [768]
  const float* outb  = (const float*)d_in[12];  // [1]
  float* outp = (float*)d_out;

  // workspace layout (floats)
  float* ws = (float*)d_ws;
  const size_t YSZ = (size_t)65536 * 128;  // 8388608
  float* y1 = ws;
  float* y2 = y1 + YSZ;
  float* y3 = y2 + YSZ;
  float* U  = y3 + YSZ;
  float* V  = U + YSZ;
  float* h1 = U;                 // h1 [131072,128] overlaps U+V (used before them)
  float* sq = V + YSZ;
  int*   idxb = (int*)(sq + 65536);
  float* g  = (float*)(idxb + 131072);
  float* ha = g + 49152;
  float* hb = ha + 49152;

  // --- conv1 ---
  pn_knn5<<<16384, 256, 0, stream>>>(x, idxb);
  pn_conv1_l1<<<16384, 256, 0, stream>>>(x, idxb, p1w1, p1b1, h1);
  pn_gemm128<true, true><<<1024, 256, 0, stream>>>(h1, p1w2, p1b2, y1);
  // --- conv2 ---
  pn_sqnorm<<<256, 256, 0, stream>>>(y1, sq);
  pn_knn128<<<512, 256, 0, stream>>>(y1, sq, idxb);
  pn_gemm128<false, false><<<512, 256, 0, stream>>>(y1, cw,          nullptr, U);
  pn_gemm128<false, false><<<512, 256, 0, stream>>>(y1, cw + 16384,  nullptr, V);
  pn_edge_max<<<8192, 256, 0, stream>>>(U, V, idxb, cb, y2);
  // --- conv3 ---
  pn_sqnorm<<<256, 256, 0, stream>>>(y2, sq);
  pn_knn128<<<512, 256, 0, stream>>>(y2, sq, idxb);
  pn_gemm128<false, false><<<512, 256, 0, stream>>>(y2, cw + 32768,  nullptr, U);
  pn_gemm128<false, false><<<512, 256, 0, stream>>>(y2, cw + 49152,  nullptr, V);
  pn_edge_max<<<8192, 256, 0, stream>>>(U, V, idxb, cb + 128, y3);
  // --- head ---
  pn_pool<<<64, 384, 0, stream>>>(y1, y2, y3, g);
  pn_bn<<<3, 256, 0, stream>>>(g, bng, bnb, ha);
  pn_dense<<<192, 256, 0, stream>>>(ha, linw + 0*589824, linb + 0*768, hb);
  pn_dense<<<192, 256, 0, stream>>>(hb, linw + 1*589824, linb + 1*768, ha);
  pn_dense<<<192, 256, 0, stream>>>(ha, linw + 2*589824, linb + 2*768, hb);
  pn_dense<<<192, 256, 0, stream>>>(hb, linw + 3*589824, linb + 3*768, ha);
  pn_dense<<<192, 256, 0, stream>>>(ha, linw + 4*589824, linb + 4*768, hb);
  pn_out<<<16, 256, 0, stream>>>(hb, outw, outb, outp);
}

// Round 3
// 1574.431 us; speedup vs baseline: 1.6136x; 1.1788x over previous
//
#include <hip/hip_runtime.h>
#include <cfloat>

// PointNet / DGCNN: B=64, N=1024, F=5, W=128, K=2, D2=768
// R3: knn128 j-split(16 slices of 64) -> grid 8192, 128i x 64j tile,
//     8x4 micro (VGPR<=128 via launch_bounds(256,4)), register-prefetch
//     k-chunks, staging pads 133/69 (stride=20 mod 32 -> <=2-way, free).
//     Per-(row,slice) top-2 merged by pn_knn_merge (ascending-slice insertion
//     keeps tie-break bit-identical). knn5 stages event x in LDS. U/V gemms
//     merged into one 1024-block launch.

__device__ __forceinline__ void top2_update(float& d1, int& j1, float& d2, int& j2,
                                            float dd, int j) {
  if (dd < d1 || (dd == d1 && j < j1)) { d2 = d1; j2 = j1; d1 = dd; j1 = j; }
  else if (dd < d2 || (dd == d2 && j < j2)) { d2 = dd; j2 = j; }
}

__device__ __forceinline__ void top2_merge_xor(float& d1, int& j1, float& d2, int& j2, int m) {
  float od1 = __shfl_xor(d1, m, 64); int oj1 = __shfl_xor(j1, m, 64);
  float od2 = __shfl_xor(d2, m, 64); int oj2 = __shfl_xor(j2, m, 64);
  bool aw = (d1 < od1) || (d1 == od1 && j1 < oj1);
  float h2d = aw ? d2 : od2;  int h2j = aw ? j2 : oj2;
  float lmd = aw ? od1 : d1;  int lmj = aw ? oj1 : j1;
  float nd1 = aw ? d1 : od1;  int nj1 = aw ? j1 : oj1;
  bool bw = (h2d < lmd) || (h2d == lmd && h2j < lmj);
  d1 = nd1; j1 = nj1;
  d2 = bw ? h2d : lmd; j2 = bw ? h2j : lmj;
}

__device__ __forceinline__ void top2_reduce_wave(float& d1, int& j1, float& d2, int& j2) {
  #pragma unroll
  for (int m = 1; m < 64; m <<= 1) top2_merge_xor(d1, j1, d2, j2, m);
}

// ---------------- KNN on 5-dim x: event x staged in LDS, one wave per row ----
__global__ __launch_bounds__(256) void pn_knn5(const float* __restrict__ x,
                                               int* __restrict__ idx) {
  __shared__ float xs[5120];
  int t = threadIdx.x;
  int b = blockIdx.x >> 8;
  int r0 = (blockIdx.x & 255) * 4;
  const float4* xb4 = (const float4*)(x + (size_t)b * 5120);
  #pragma unroll
  for (int s = 0; s < 5; ++s) ((float4*)xs)[t + 256 * s] = xb4[t + 256 * s];
  __syncthreads();
  int wv = t >> 6, lane = t & 63;
  int i = r0 + wv;
  float x0 = xs[i*5+0], x1 = xs[i*5+1], x2 = xs[i*5+2], x3 = xs[i*5+3], x4 = xs[i*5+4];
  float d1 = FLT_MAX, d2 = FLT_MAX; int j1 = 0x7fffffff, j2 = 0x7fffffff;
  for (int tS = 0; tS < 16; ++tS) {
    int j = tS * 64 + lane;
    const float* xj = &xs[j * 5];
    float f0 = xj[0] - x0, f1 = xj[1] - x1, f2 = xj[2] - x2, f3 = xj[3] - x3, f4 = xj[4] - x4;
    float dd = f0*f0 + f1*f1 + f2*f2 + f3*f3 + f4*f4;
    top2_update(d1, j1, d2, j2, dd, j);
  }
  top2_reduce_wave(d1, j1, d2, j2);
  if (lane == 0) {
    int r = b * 1024 + i;
    idx[r*2+0] = j1; idx[r*2+1] = j2;
  }
}

// ---------------- conv1 layer1 ----------------
__global__ __launch_bounds__(256) void pn_conv1_l1(const float* __restrict__ x,
                                                   const int* __restrict__ idx,
                                                   const float* __restrict__ w1,
                                                   const float* __restrict__ b1,
                                                   float* __restrict__ h1) {
  __shared__ float Ws[1280];
  __shared__ float Bs[128];
  for (int s = threadIdx.x; s < 1280; s += 256) Ws[s] = w1[s];
  if (threadIdx.x < 128) Bs[threadIdx.x] = b1[threadIdx.x];
  __syncthreads();
  int c = threadIdx.x & 127, rr = threadIdx.x >> 7;
  #pragma unroll
  for (int s = 0; s < 4; ++s) {
    int r = blockIdx.x * 8 + s * 2 + rr;
    int i = r >> 1, k = r & 1;
    int j = idx[i*2 + k];
    int jrow = ((i >> 10) << 10) + j;
    const float* xi = x + (size_t)i * 5;
    const float* xj = x + (size_t)jrow * 5;
    float acc = Bs[c];
    #pragma unroll
    for (int f = 0; f < 5; ++f) {
      float a = xi[f];
      float d = xj[f] - a;
      acc = fmaf(a, Ws[f*128 + c], acc);
      acc = fmaf(d, Ws[(5+f)*128 + c], acc);
    }
    h1[(size_t)r * 128 + c] = fmaxf(acc, 0.0f);
  }
}

// ---------------- GEMM core: A[128 rows] @ W[128,128] ----------------
template<bool RELU, bool PAIRMAX>
__device__ __forceinline__ void gemm128_core(int bid, const float* __restrict__ A,
                                             const float* __restrict__ W,
                                             const float* __restrict__ bias,
                                             float* __restrict__ out) {
  __shared__ float As[32][133];
  __shared__ float Wsb[32][133];
  int t = threadIdx.x;
  int rg = t >> 4;
  int cg = t & 15;
  float acc[8][8];
  #pragma unroll
  for (int a = 0; a < 8; ++a)
    #pragma unroll
    for (int b = 0; b < 8; ++b) acc[a][b] = 0.f;
  size_t r0 = (size_t)bid * 128;
  int ra = t >> 1, hf = t & 1;
  int wb = t >> 3, cp = t & 7;
  for (int w0 = 0; w0 < 128; w0 += 32) {
    const float* asrc = A + (r0 + ra) * 128 + w0 + hf * 16;
    #pragma unroll
    for (int q = 0; q < 4; ++q) {
      float4 v = ((const float4*)asrc)[q];
      int wi = hf * 16 + q * 4;
      As[wi+0][ra] = v.x; As[wi+1][ra] = v.y; As[wi+2][ra] = v.z; As[wi+3][ra] = v.w;
    }
    const float* wsrc = W + (size_t)(w0 + wb) * 128 + cp * 16;
    #pragma unroll
    for (int q = 0; q < 4; ++q)
      *(float4*)&Wsb[wb][cp*16 + q*4] = ((const float4*)wsrc)[q];
    __syncthreads();
    #pragma unroll
    for (int w = 0; w < 32; ++w) {
      float av[8], wv[8];
      *(float4*)&av[0] = *(const float4*)&As[w][rg*8];
      *(float4*)&av[4] = *(const float4*)&As[w][rg*8+4];
      *(float4*)&wv[0] = *(const float4*)&Wsb[w][cg*4];
      *(float4*)&wv[4] = *(const float4*)&Wsb[w][64 + cg*4];
      #pragma unroll
      for (int ri = 0; ri < 8; ++ri)
        #pragma unroll
        for (int ci = 0; ci < 8; ++ci)
          acc[ri][ci] = fmaf(av[ri], wv[ci], acc[ri][ci]);
    }
    __syncthreads();
  }
  float blo[4], bhi[4];
  #pragma unroll
  for (int ci = 0; ci < 4; ++ci) {
    blo[ci] = bias ? bias[cg*4 + ci] : 0.f;
    bhi[ci] = bias ? bias[64 + cg*4 + ci] : 0.f;
  }
  if (PAIRMAX) {
    #pragma unroll
    for (int ri = 0; ri < 8; ri += 2) {
      size_t orow = (r0 + rg*8 + ri) >> 1;
      float lo[4], hi[4];
      #pragma unroll
      for (int ci = 0; ci < 4; ++ci) {
        float v0 = acc[ri][ci]   + blo[ci];
        float v1 = acc[ri+1][ci] + blo[ci];
        lo[ci] = fmaxf(fmaxf(v0, v1), 0.f);
        float w0v = acc[ri][ci+4]   + bhi[ci];
        float w1v = acc[ri+1][ci+4] + bhi[ci];
        hi[ci] = fmaxf(fmaxf(w0v, w1v), 0.f);
      }
      *(float4*)&out[orow*128 + cg*4]      = *(float4*)lo;
      *(float4*)&out[orow*128 + 64 + cg*4] = *(float4*)hi;
    }
  } else {
    #pragma unroll
    for (int ri = 0; ri < 8; ++ri) {
      size_t row = r0 + rg*8 + ri;
      float lo[4], hi[4];
      #pragma unroll
      for (int ci = 0; ci < 4; ++ci) {
        float v0 = acc[ri][ci]   + blo[ci];
        float v1 = acc[ri][ci+4] + bhi[ci];
        lo[ci] = RELU ? fmaxf(v0, 0.f) : v0;
        hi[ci] = RELU ? fmaxf(v1, 0.f) : v1;
      }
      *(float4*)&out[row*128 + cg*4]      = *(float4*)lo;
      *(float4*)&out[row*128 + 64 + cg*4] = *(float4*)hi;
    }
  }
}

__global__ __launch_bounds__(256) void pn_gemm128_bias(const float* __restrict__ A,
                                                       const float* __restrict__ W,
                                                       const float* __restrict__ bias,
                                                       float* __restrict__ out) {
  gemm128_core<true, true>(blockIdx.x, A, W, bias, out);
}

__global__ __launch_bounds__(256) void pn_gemm128_uv(const float* __restrict__ A,
                                                     const float* __restrict__ Wb,
                                                     float* __restrict__ U,
                                                     float* __restrict__ V) {
  int which = blockIdx.x >> 9;
  gemm128_core<false, false>(blockIdx.x & 511, A, Wb + (which << 14), nullptr,
                             which ? V : U);
}

// ---------------- row squared norms ----------------
__global__ __launch_bounds__(256) void pn_sqnorm(const float* __restrict__ y,
                                                 float* __restrict__ sq) {
  int r = blockIdx.x * 256 + threadIdx.x;
  const float4* p = (const float4*)(y + (size_t)r * 128);
  float s = 0.f;
  #pragma unroll
  for (int q = 0; q < 32; ++q) {
    float4 v = p[q];
    s += v.x*v.x + v.y*v.y + v.z*v.z + v.w*v.w;
  }
  sq[r] = s;
}

// ---------------- KNN-128 Gram tile: 128 i x 64 j, j-split 16 ----------------
// grid = 64 ev x 16 jh x 8 itile = 8192 blocks.
__global__ __launch_bounds__(256, 4) void pn_knn128(const float* __restrict__ Y,
                                                    const float* __restrict__ sqn,
                                                    int4* __restrict__ cand) {
  __shared__ float As[32][133];   // [k][i]
  __shared__ float Bs[32][69];    // [k][j]
  int t = threadIdx.x;
  int rg = t >> 4, cg = t & 15;
  int b  = blockIdx.x >> 7;
  int jh = (blockIdx.x >> 3) & 15;
  int it = blockIdx.x & 7;
  int i0 = it * 128, j0 = jh * 64;
  const float* Yb  = Y   + (size_t)b * (1024 * 128);
  const float* sqb = sqn + b * 1024;

  float sqi[8];
  #pragma unroll
  for (int ri = 0; ri < 8; ++ri) sqi[ri] = sqb[i0 + rg*8 + ri];

  float acc[8][4];
  #pragma unroll
  for (int a = 0; a < 8; ++a)
    #pragma unroll
    for (int c = 0; c < 4; ++c) acc[a][c] = 0.f;

  int rowA = t >> 3, kqA = (t & 7) * 4;
  float4 pA[4], pB[2];
  #pragma unroll
  for (int q = 0; q < 4; ++q)
    pA[q] = *(const float4*)&Yb[(size_t)(i0 + rowA + 32*q) * 128 + kqA];
  #pragma unroll
  for (int q = 0; q < 2; ++q)
    pB[q] = *(const float4*)&Yb[(size_t)(j0 + rowA + 32*q) * 128 + kqA];

  for (int k0c = 0; k0c < 4; ++k0c) {
    __syncthreads();
    #pragma unroll
    for (int q = 0; q < 4; ++q) {
      int row = rowA + 32*q;
      As[kqA+0][row] = pA[q].x; As[kqA+1][row] = pA[q].y;
      As[kqA+2][row] = pA[q].z; As[kqA+3][row] = pA[q].w;
    }
    #pragma unroll
    for (int q = 0; q < 2; ++q) {
      int row = rowA + 32*q;
      Bs[kqA+0][row] = pB[q].x; Bs[kqA+1][row] = pB[q].y;
      Bs[kqA+2][row] = pB[q].z; Bs[kqA+3][row] = pB[q].w;
    }
    __syncthreads();
    if (k0c < 3) {
      int kn = (k0c + 1) * 32;
      #pragma unroll
      for (int q = 0; q < 4; ++q)
        pA[q] = *(const float4*)&Yb[(size_t)(i0 + rowA + 32*q) * 128 + kn + kqA];
      #pragma unroll
      for (int q = 0; q < 2; ++q)
        pB[q] = *(const float4*)&Yb[(size_t)(j0 + rowA + 32*q) * 128 + kn + kqA];
    }
    #pragma unroll
    for (int k = 0; k < 32; ++k) {
      float av[8], bv[4];
      *(float4*)&av[0] = *(const float4*)&As[k][rg*8];
      *(float4*)&av[4] = *(const float4*)&As[k][rg*8+4];
      *(float4*)&bv[0] = *(const float4*)&Bs[k][cg*4];
      #pragma unroll
      for (int ri = 0; ri < 8; ++ri)
        #pragma unroll
        for (int ci = 0; ci < 4; ++ci)
          acc[ri][ci] = fmaf(av[ri], bv[ci], acc[ri][ci]);
    }
  }

  float4 sqj = *(const float4*)&sqb[j0 + cg*4];
  float sj[4] = {sqj.x, sqj.y, sqj.z, sqj.w};
  #pragma unroll
  for (int ri = 0; ri < 8; ++ri) {
    float d1 = FLT_MAX, d2 = FLT_MAX; int j1 = 0x7fffffff, j2 = 0x7fffffff;
    #pragma unroll
    for (int ci = 0; ci < 4; ++ci) {
      int j = j0 + cg*4 + ci;
      float dd = sqi[ri] + sj[ci] - 2.0f * acc[ri][ci];
      top2_update(d1, j1, d2, j2, dd, j);
    }
    top2_merge_xor(d1, j1, d2, j2, 1);
    top2_merge_xor(d1, j1, d2, j2, 2);
    top2_merge_xor(d1, j1, d2, j2, 4);
    top2_merge_xor(d1, j1, d2, j2, 8);
    if (cg == 0) {
      int row = b * 1024 + i0 + rg*8 + ri;
      cand[(size_t)jh * 65536 + row] =
        make_int4(__float_as_int(d1), __float_as_int(d2), j1, j2);
    }
  }
}

__global__ __launch_bounds__(256) void pn_knn_merge(const int4* __restrict__ cand,
                                                    int nslice,
                                                    int* __restrict__ idx) {
  int r = blockIdx.x * 256 + threadIdx.x;
  float d1 = FLT_MAX, d2 = FLT_MAX; int j1 = 0x7fffffff, j2 = 0x7fffffff;
  for (int s = 0; s < nslice; ++s) {
    int4 c = cand[(size_t)s * 65536 + r];
    top2_update(d1, j1, d2, j2, __int_as_float(c.x), c.z);
    top2_update(d1, j1, d2, j2, __int_as_float(c.y), c.w);
  }
  idx[r*2+0] = j1; idx[r*2+1] = j2;
}

// ---------------- edge epilogue ----------------
__global__ __launch_bounds__(256) void pn_edge_max(const float* __restrict__ U,
                                                   const float* __restrict__ V,
                                                   const int* __restrict__ idx,
                                                   const float* __restrict__ bias,
                                                   float* __restrict__ y) {
  int gid = blockIdx.x * 256 + threadIdx.x;
  int i = gid >> 5, c4 = (gid & 31) << 2;
  int base = (i >> 10) << 10;
  int j0 = idx[i*2+0], j1 = idx[i*2+1];
  float4 u  = *(const float4*)&U[(size_t)i*128 + c4];
  float4 vi = *(const float4*)&V[(size_t)i*128 + c4];
  float4 v0 = *(const float4*)&V[(size_t)(base + j0)*128 + c4];
  float4 v1 = *(const float4*)&V[(size_t)(base + j1)*128 + c4];
  float4 bb = *(const float4*)&bias[c4];
  float4 o;
  o.x = fmaxf(fmaxf(u.x + v0.x - vi.x + bb.x, u.x + v1.x - vi.x + bb.x), 0.f);
  o.y = fmaxf(fmaxf(u.y + v0.y - vi.y + bb.y, u.y + v1.y - vi.y + bb.y), 0.f);
  o.z = fmaxf(fmaxf(u.z + v0.z - vi.z + bb.z, u.z + v1.z - vi.z + bb.z), 0.f);
  o.w = fmaxf(fmaxf(u.w + v0.w - vi.w + bb.w, u.w + v1.w - vi.w + bb.w), 0.f);
  *(float4*)&y[(size_t)i*128 + c4] = o;
}

// ---------------- pooling ----------------
__global__ __launch_bounds__(384) void pn_pool(const float* __restrict__ y1,
                                               const float* __restrict__ y2,
                                               const float* __restrict__ y3,
                                               float* __restrict__ g) {
  int b = blockIdx.x, c = threadIdx.x;
  const float* src = (c < 128) ? (y1 + (size_t)b * 1024 * 128 + c)
                   : (c < 256) ? (y2 + (size_t)b * 1024 * 128 + (c - 128))
                               : (y3 + (size_t)b * 1024 * 128 + (c - 256));
  float s = 0.f, mx = -FLT_MAX;
  for (int n = 0; n < 1024; ++n) {
    float v = src[(size_t)n * 128];
    s += v; mx = fmaxf(mx, v);
  }
  g[b*768 + c] = s * (1.0f / 1024.0f);
  g[b*768 + 384 + c] = mx;
}

// ---------------- batchnorm ----------------
__global__ __launch_bounds__(256) void pn_bn(const float* __restrict__ g,
                                             const float* __restrict__ gamma,
                                             const float* __restrict__ beta,
                                             float* __restrict__ out) {
  int c = blockIdx.x * 256 + threadIdx.x;
  float mu = 0.f;
  for (int b = 0; b < 64; ++b) mu += g[b*768 + c];
  mu *= (1.0f / 64.0f);
  float var = 0.f;
  for (int b = 0; b < 64; ++b) { float d = g[b*768 + c] - mu; var += d * d; }
  var *= (1.0f / 64.0f);
  float sc = (1.0f / sqrtf(var + 1e-5f)) * gamma[c];
  float sh = beta[c];
  for (int b = 0; b < 64; ++b) out[b*768 + c] = (g[b*768 + c] - mu) * sc + sh;
}

// ---------------- dense 768->768 (+leaky) ----------------
__global__ __launch_bounds__(256) void pn_dense(const float* __restrict__ h,
                                                const float* __restrict__ W,
                                                const float* __restrict__ bias,
                                                float* __restrict__ out) {
  int b = blockIdx.x / 3;
  int c = (blockIdx.x % 3) * 256 + threadIdx.x;
  const float* hb = h + (size_t)b * 768;
  float acc = bias[c];
  for (int w = 0; w < 768; ++w) acc = fmaf(hb[w], W[(size_t)w*768 + c], acc);
  acc = acc > 0.f ? acc : 0.01f * acc;
  out[b*768 + c] = acc;
}

// ---------------- final 768->1 ----------------
__global__ __launch_bounds__(256) void pn_out(const float* __restrict__ h,
                                              const float* __restrict__ ow,
                                              const float* __restrict__ ob,
                                              float* __restrict__ out) {
  int wid = blockIdx.x * 4 + (threadIdx.x >> 6);
  int lane = threadIdx.x & 63;
  const float* hb = h + (size_t)wid * 768;
  float s = 0.f;
  #pragma unroll
  for (int q = 0; q < 12; ++q) {
    int w = q * 64 + lane;
    s = fmaf(hb[w], ow[w], s);
  }
  #pragma unroll
  for (int m = 1; m < 64; m <<= 1) s += __shfl_xor(s, m, 64);
  if (lane == 0) out[wid] = s + ob[0];
}

extern "C" void kernel_launch(void* const* d_in, const int* in_sizes, int n_in,
                              void* d_out, int out_size, void* d_ws, size_t ws_size,
                              hipStream_t stream) {
  (void)in_sizes; (void)n_in; (void)out_size; (void)ws_size;
  const float* x     = (const float*)d_in[0];
  const float* p1w1  = (const float*)d_in[1];
  const float* p1b1  = (const float*)d_in[2];
  const float* p1w2  = (const float*)d_in[3];
  const float* p1b2  = (const float*)d_in[4];
  const float* cw    = (const float*)d_in[5];
  const float* cb    = (const float*)d_in[6];
  const float* bng   = (const float*)d_in[7];
  const float* bnb   = (const float*)d_in[8];
  const float* linw  = (const float*)d_in[9];
  const float* linb  = (const float*)d_in[10];
  const float* outw  = (const float*)d_in[11];
  const float* outb  = (const float*)d_in[12];
  float* outp = (float*)d_out;

  float* ws = (float*)d_ws;
  const size_t YSZ = (size_t)65536 * 128;
  float* y1 = ws;
  float* y2 = y1 + YSZ;
  float* y3 = y2 + YSZ;
  float* U  = y3 + YSZ;
  float* V  = U + YSZ;
  float* h1 = U;                     // conv1 scratch, dead after first gemm
  int4*  cand = (int4*)V;            // knn scratch (16 MB), dead before V write
  float* sq = V + YSZ;
  int*   idxb = (int*)(sq + 65536);
  float* g  = (float*)(idxb + 131072);
  float* ha = g + 49152;
  float* hb = ha + 49152;

  // --- conv1 ---
  pn_knn5<<<16384, 256, 0, stream>>>(x, idxb);
  pn_conv1_l1<<<16384, 256, 0, stream>>>(x, idxb, p1w1, p1b1, h1);
  pn_gemm128_bias<<<1024, 256, 0, stream>>>(h1, p1w2, p1b2, y1);
  // --- conv2 ---
  pn_sqnorm<<<256, 256, 0, stream>>>(y1, sq);
  pn_knn128<<<8192, 256, 0, stream>>>(y1, sq, cand);
  pn_knn_merge<<<256, 256, 0, stream>>>(cand, 16, idxb);
  pn_gemm128_uv<<<1024, 256, 0, stream>>>(y1, cw, U, V);
  pn_edge_max<<<8192, 256, 0, stream>>>(U, V, idxb, cb, y2);
  // --- conv3 ---
  pn_sqnorm<<<256, 256, 0, stream>>>(y2, sq);
  pn_knn128<<<8192, 256, 0, stream>>>(y2, sq, cand);
  pn_knn_merge<<<256, 256, 0, stream>>>(cand, 16, idxb);
  pn_gemm128_uv<<<1024, 256, 0, stream>>>(y2, cw + 32768, U, V);
  pn_edge_max<<<8192, 256, 0, stream>>>(U, V, idxb, cb + 128, y3);
  // --- head ---
  pn_pool<<<64, 384, 0, stream>>>(y1, y2, y3, g);
  pn_bn<<<3, 256, 0, stream>>>(g, bng, bnb, ha);
  pn_dense<<<192, 256, 0, stream>>>(ha, linw + 0*589824, linb + 0*768, hb);
  pn_dense<<<192, 256, 0, stream>>>(hb, linw + 1*589824, linb + 1*768, ha);
  pn_dense<<<192, 256, 0, stream>>>(ha, linw + 2*589824, linb + 2*768, hb);
  pn_dense<<<192, 256, 0, stream>>>(hb, linw + 3*589824, linb + 3*768, ha);
  pn_dense<<<192, 256, 0, stream>>>(ha, linw + 4*589824, linb + 4*768, hb);
  pn_out<<<16, 256, 0, stream>>>(hb, outw, outb, outp);
}